// Round 8
// baseline (132.165 us; speedup 1.0000x reference)
//
#include <hip/hip_runtime.h>
#include <hip/hip_bf16.h>

typedef float f32x4 __attribute__((ext_vector_type(4)));
typedef __bf16 bf16x8 __attribute__((ext_vector_type(8)));

typedef __attribute__((address_space(1))) const unsigned int as1_uint;
typedef __attribute__((address_space(3))) unsigned int as3_uint;

// ---------------------------------------------------------------------------
// GEMM1: h1(256x128) = x(256x256) @ w1(128x256)^T + b1
// ---------------------------------------------------------------------------
__global__ __launch_bounds__(128) void gemm1_k(const float* __restrict__ x,
                                               const float* __restrict__ w1,
                                               const float* __restrict__ b1,
                                               float* __restrict__ h1) {
    __shared__ float xs[256];
    const int m = blockIdx.x, t = threadIdx.x;
    xs[t] = x[m * 256 + t];
    xs[t + 128] = x[m * 256 + 128 + t];
    __syncthreads();
    float acc = b1[t];
    const float4* wr = (const float4*)(w1 + t * 256);
#pragma unroll 8
    for (int k4 = 0; k4 < 64; ++k4) {
        float4 w = wr[k4];
        acc += xs[k4 * 4 + 0] * w.x + xs[k4 * 4 + 1] * w.y +
               xs[k4 * 4 + 2] * w.z + xs[k4 * 4 + 3] * w.w;
    }
    h1[m * 128 + t] = acc;
}

// ---------------------------------------------------------------------------
// GEMM2: h2b = bf16 pre-swizzled "LDS image" of h1 @ w2^T + b2.
// byte(m, n) = (n>>6)*32768 + ((m*128 + ((n&63)>>3)*16) ^ ((m&7)<<4)) + (n&7)*2
// ---------------------------------------------------------------------------
__global__ __launch_bounds__(256) void gemm2_k(const float* __restrict__ h1,
                                               const float* __restrict__ w2,
                                               const float* __restrict__ b2,
                                               char* __restrict__ h2b) {
    __shared__ float As[64][129];
    __shared__ float Bs[64][129];
    const int nb = blockIdx.x, mb = blockIdx.y, t = threadIdx.x;
#pragma unroll
    for (int i = 0; i < 8; ++i) {
        int idx = i * 256 + t;
        int row = idx >> 5, c4 = (idx & 31) * 4;
        float4 a = *(const float4*)(h1 + (mb * 64 + row) * 128 + c4);
        As[row][c4 + 0] = a.x; As[row][c4 + 1] = a.y;
        As[row][c4 + 2] = a.z; As[row][c4 + 3] = a.w;
        float4 bv = *(const float4*)(w2 + (nb * 64 + row) * 128 + c4);
        Bs[row][c4 + 0] = bv.x; Bs[row][c4 + 1] = bv.y;
        Bs[row][c4 + 2] = bv.z; Bs[row][c4 + 3] = bv.w;
    }
    __syncthreads();
    const int tx = t & 15, ty = t >> 4;
    float acc[4][4] = {};
#pragma unroll 4
    for (int k = 0; k < 128; ++k) {
        float a[4], b[4];
#pragma unroll
        for (int i = 0; i < 4; ++i) a[i] = As[ty * 4 + i][k];
#pragma unroll
        for (int j = 0; j < 4; ++j) b[j] = Bs[tx * 4 + j][k];
#pragma unroll
        for (int i = 0; i < 4; ++i)
#pragma unroll
            for (int j = 0; j < 4; ++j) acc[i][j] += a[i] * b[j];
    }
#pragma unroll
    for (int i = 0; i < 4; ++i)
#pragma unroll
        for (int j = 0; j < 4; ++j) {
            int m = mb * 64 + ty * 4 + i;
            int n = nb * 64 + tx * 4 + j;
            float v = acc[i][j] + b2[n];
            int kb = n >> 6, r = n & 63;
            int byte = kb * 32768 + ((m * 128 + (r >> 3) * 16) ^ ((m & 7) << 4)) + (r & 7) * 2;
            *(__bf16*)(h2b + byte) = (__bf16)v;
        }
}

// ---------------------------------------------------------------------------
// GEMM3 v7: KS=2 (2 blocks/CU) + counted-vmcnt pipeline, W loads are NORMAL
// compiler loads (no asm-pending-register hazard); waits are manual asm.
// Per step: ISSUE_A(t+1)[4 dma] ; loadW(t+2)[2 loads, pinned] ; MFMA(t) ;
// storeW(t+1) [compiler's own counted wait retires W(t+1)] ;
// asm vmcnt(2) [retires A(t+1), W(t+2) stays in flight] ; lgkm0 ; s_barrier.
// Invariant entering step t: only W(t+1):2 outstanding.
// ---------------------------------------------------------------------------
__global__ __launch_bounds__(512, 1) void gemm3_k(const char* __restrict__ Ab,
                                                  const float* __restrict__ W,
                                                  char* __restrict__ parts) {
    __shared__ __align__(16) char lds[81920];  // A dbuf 2x32KB @0; W dbuf 2x8KB @65536
    const int tid = threadIdx.x;
    const int nb = blockIdx.x >> 1, ks = blockIdx.x & 1;
    const int n0 = nb * 64;
    const int lane = tid & 63, wid = tid >> 6;
    const int mrow = tid >> 3, kb8 = tid & 7;
    const int kt0 = ks * 32;
    const int lr = lane & 15, lq = lane >> 4;
    const int wm = wid >> 1, wn = wid & 1;

    const float* Wlane = W + (size_t)(n0 + mrow) * 4096 + kb8 * 8;

#define ISSUE_A(kt, buf)                                                            \
    {                                                                               \
        const char* _s = Ab + (kt) * 32768 + wid * 4096 + lane * 16;                \
        char* _d = lds + (buf) * 32768 + wid * 4096;                                \
        __builtin_amdgcn_global_load_lds((as1_uint*)(_s), (as3_uint*)(_d), 16, 0, 0);             \
        __builtin_amdgcn_global_load_lds((as1_uint*)(_s + 1024), (as3_uint*)(_d + 1024), 16, 0, 0); \
        __builtin_amdgcn_global_load_lds((as1_uint*)(_s + 2048), (as3_uint*)(_d + 2048), 16, 0, 0); \
        __builtin_amdgcn_global_load_lds((as1_uint*)(_s + 3072), (as3_uint*)(_d + 3072), 16, 0, 0); \
    }

#define LOADW(d0, d1, kt)                                 \
    {                                                     \
        const float* _q = Wlane + (size_t)(kt) * 64;      \
        d0 = *(const float4*)_q;                          \
        d1 = *(const float4*)(_q + 4);                    \
    }

    auto storeW2 = [&](const float4& a, const float4& b, int buf) {
        bf16x8 p;
        p[0] = (__bf16)a.x; p[1] = (__bf16)a.y; p[2] = (__bf16)a.z; p[3] = (__bf16)a.w;
        p[4] = (__bf16)b.x; p[5] = (__bf16)b.y; p[6] = (__bf16)b.z; p[7] = (__bf16)b.w;
        *(bf16x8*)(lds + 65536 + buf * 8192 +
                   ((mrow * 128 + kb8 * 16) ^ ((mrow & 7) << 4))) = p;
    };

    f32x4 acc[4][2];
    const f32x4 zero = {0.f, 0.f, 0.f, 0.f};
#pragma unroll
    for (int mi = 0; mi < 4; ++mi)
#pragma unroll
        for (int ni = 0; ni < 2; ++ni) acc[mi][ni] = zero;

    auto mfma_tile = [&](const char* Ac, const char* Wc) {
#pragma unroll
        for (int kk = 0; kk < 2; ++kk) {
            const int kb = kk * 4 + lq;
            bf16x8 af[4], bfv[2];
#pragma unroll
            for (int mi = 0; mi < 4; ++mi) {
                int m = wm * 64 + mi * 16 + lr;
                af[mi] = *(const bf16x8*)(Ac + ((m * 128 + kb * 16) ^ ((m & 7) << 4)));
            }
#pragma unroll
            for (int ni = 0; ni < 2; ++ni) {
                int n = wn * 32 + ni * 16 + lr;
                bfv[ni] = *(const bf16x8*)(Wc + ((n * 128 + kb * 16) ^ ((n & 7) << 4)));
            }
#pragma unroll
            for (int mi = 0; mi < 4; ++mi)
#pragma unroll
                for (int ni = 0; ni < 2; ++ni)
                    acc[mi][ni] = __builtin_amdgcn_mfma_f32_16x16x32_bf16(
                        af[mi], bfv[ni], acc[mi][ni], 0, 0, 0);
        }
    };

    float4 wE0, wE1, wO0, wO1;

    // ---- prologue: establish invariant {only W(1):2 outstanding} ----
    LOADW(wE0, wE1, kt0);                               // [W0:2]
    ISSUE_A(kt0, 0);                                    // [W0:2, A0:4]
    storeW2(wE0, wE1, 0);                               // compiler wait retires W0
    LOADW(wO0, wO1, kt0 + 1);                           // [A0:4, W1:2]
    asm volatile("s_waitcnt vmcnt(2)" ::: "memory");    // retire A0; W1 flies
    __builtin_amdgcn_sched_barrier(0);
    asm volatile("s_waitcnt lgkmcnt(0)" ::: "memory");
    __builtin_amdgcn_sched_barrier(0);
    __builtin_amdgcn_s_barrier();

// step tt: consume tile tt (buf CUR); store W(tt+1) from WS; load W(tt+2) to WL.
#define G3_STEP(tt, CUR, WS0, WS1, WL0, WL1)                                   \
    {                                                                          \
        ISSUE_A(kt0 + (tt) + 1, (CUR) ^ 1);                                    \
        LOADW(WL0, WL1, kt0 + (tt) + 2);                                       \
        __builtin_amdgcn_sched_barrier(0);                                     \
        mfma_tile(lds + (CUR) * 32768, lds + 65536 + (CUR) * 8192);            \
        storeW2(WS0, WS1, (CUR) ^ 1);                                          \
        asm volatile("s_waitcnt vmcnt(2)" ::: "memory");                       \
        __builtin_amdgcn_sched_barrier(0);                                     \
        asm volatile("s_waitcnt lgkmcnt(0)" ::: "memory");                     \
        __builtin_amdgcn_sched_barrier(0);                                     \
        __builtin_amdgcn_s_barrier();                                          \
    }

#pragma unroll 1
    for (int i = 0; i < 15; ++i) {
        G3_STEP(2 * i, 0, wO0, wO1, wE0, wE1);
        G3_STEP(2 * i + 1, 1, wE0, wE1, wO0, wO1);
    }
    // step 30 (no further W load): store W(31); drain A(31)
    {
        ISSUE_A(kt0 + 31, 1);
        mfma_tile(lds, lds + 65536);                    // tile 30 (buf 0)
        storeW2(wO0, wO1, 1);                           // compiler wait retires W31
        asm volatile("s_waitcnt vmcnt(0)" ::: "memory");
        __builtin_amdgcn_sched_barrier(0);
        asm volatile("s_waitcnt lgkmcnt(0)" ::: "memory");
        __builtin_amdgcn_sched_barrier(0);
        __builtin_amdgcn_s_barrier();
    }
    mfma_tile(lds + 32768, lds + 65536 + 8192);         // tile 31

#undef G3_STEP
#undef LOADW
#undef ISSUE_A

    __bf16* P = (__bf16*)(parts + ks * 8388608);
#pragma unroll
    for (int mi = 0; mi < 4; ++mi)
#pragma unroll
        for (int ni = 0; ni < 2; ++ni) {
            const int n = n0 + wn * 32 + ni * 16 + lr;
#pragma unroll
            for (int r = 0; r < 4; ++r) {
                int m = wm * 64 + mi * 16 + lq * 4 + r;
                P[m * 16384 + n] = (__bf16)acc[mi][ni][r];
            }
        }
}

// ---------------------------------------------------------------------------
// Fused conv x5 (bf16 MFMA) + square + Sinkhorn. One block per batch element.
// Staging sums the two gemm3 partials and adds b3.
// ---------------------------------------------------------------------------
template <int CIN, int COUT, int DIL, int MT, int NT>
__device__ __forceinline__ void conv_core(const char* xt, char* wl,
                                          const float* __restrict__ w,
                                          f32x4 (&acc)[MT][NT], int tid) {
    constexpr int RB = CIN * 2;
    const int lane = tid & 63, wid = tid >> 6;
    const int lr = lane & 15, lq = lane >> 4;
    const int cobase = wid * (COUT / 4);
    const f32x4 zero = {0.f, 0.f, 0.f, 0.f};
#pragma unroll
    for (int mi = 0; mi < MT; ++mi)
#pragma unroll
        for (int ni = 0; ni < NT; ++ni) acc[mi][ni] = zero;

    for (int cic = 0; cic < CIN / 32; ++cic) {
        for (int idx = tid; idx < COUT * 4; idx += 256) {
            int co = idx >> 2, cib = idx & 3, ci0 = cic * 32 + cib * 8;
            const float* src = w + co * (CIN * 3) + ci0 * 3;
            float v[24];
#pragma unroll
            for (int u = 0; u < 6; ++u) {
                float4 f = *(const float4*)(src + u * 4);
                v[u * 4 + 0] = f.x; v[u * 4 + 1] = f.y;
                v[u * 4 + 2] = f.z; v[u * 4 + 3] = f.w;
            }
#pragma unroll
            for (int tp = 0; tp < 3; ++tp) {
                bf16x8 pk;
#pragma unroll
                for (int j = 0; j < 8; ++j) pk[j] = (__bf16)v[j * 3 + tp];
                *(bf16x8*)(wl + ((tp * 4 + cib) * COUT + co) * 16) = pk;
            }
        }
        __syncthreads();
#pragma unroll
        for (int tp = 0; tp < 3; ++tp) {
            bf16x8 af[MT];
#pragma unroll
            for (int mi = 0; mi < MT; ++mi)
                af[mi] = *(const bf16x8*)(wl + ((tp * 4 + lq) * COUT + cobase + mi * 16 + lr) * 16);
            bf16x8 bfr[NT];
#pragma unroll
            for (int ni = 0; ni < NT; ++ni) {
                int colX = ni * 16 + lr + tp * DIL;
                bfr[ni] = *(const bf16x8*)(xt + ((colX * RB + (cic * 4 + lq) * 16) ^ ((colX & 7) << 4)));
            }
#pragma unroll
            for (int mi = 0; mi < MT; ++mi)
#pragma unroll
                for (int ni = 0; ni < NT; ++ni)
                    acc[mi][ni] = __builtin_amdgcn_mfma_f32_16x16x32_bf16(
                        af[mi], bfr[ni], acc[mi][ni], 0, 0, 0);
        }
        __syncthreads();
    }
}

template <int COUT, int LOUT, int MT, int NT>
__device__ __forceinline__ void write_xt(char* xt_out, const f32x4 (&acc)[MT][NT],
                                         const float* __restrict__ bias, int tid) {
    constexpr int RBO = COUT * 2;
    const int lane = tid & 63, wid = tid >> 6;
    const int lr = lane & 15, lq = lane >> 4;
    const int cobase = wid * (COUT / 4);
#pragma unroll
    for (int mi = 0; mi < MT; ++mi)
#pragma unroll
        for (int ni = 0; ni < NT; ++ni) {
            int l = ni * 16 + lr;
            if (l < LOUT) {
#pragma unroll
                for (int r = 0; r < 4; ++r) {
                    int co = cobase + mi * 16 + lq * 4 + r;
                    float y = acc[mi][ni][r] + bias[co];
                    int byte = (l * RBO + ((co >> 3) << 4) + (co & 7) * 2) ^ ((l & 7) << 4);
                    *(__bf16*)(xt_out + byte) = (__bf16)y;
                }
            }
        }
}

__global__ __launch_bounds__(256, 1) void convsink_k(
    const char* __restrict__ parts, const float* __restrict__ b3,
    const float* __restrict__ cw1, const float* __restrict__ cb1,
    const float* __restrict__ cw2, const float* __restrict__ cb2,
    const float* __restrict__ cw3, const float* __restrict__ cb3,
    const float* __restrict__ cw4, const float* __restrict__ cb4,
    const float* __restrict__ cw5, const float* __restrict__ cb5,
    float* __restrict__ out) {
    __shared__ __align__(16) char lds[34816 + 31488 + 36864 + 16640];
    char* xtA = lds;
    char* xtB = lds + 34816;
    char* wl = lds + 34816 + 31488;
    float* S = (float*)(lds + 34816 + 31488 + 36864);

    const int b = blockIdx.x, tid = threadIdx.x;
    const __bf16* p0 = (const __bf16*)parts + (size_t)b * 16384;
    const __bf16* p1 = (const __bf16*)(parts + 8388608) + (size_t)b * 16384;

#pragma unroll
    for (int i = 0; i < 8; ++i) {
        int idx = i * 256 + tid;
        int l = idx & 127, cib = idx >> 7;
        bf16x8 p;
#pragma unroll
        for (int j = 0; j < 8; ++j) {
            int n = (cib * 8 + j) * 128 + l;
            float v = (float)p0[n] + (float)p1[n] + b3[n];
            p[j] = (__bf16)v;
        }
        *(bf16x8*)(xtA + ((l * 256 + cib * 16) ^ ((l & 7) << 4))) = p;
    }
    __syncthreads();

    {
        f32x4 acc[3][5];
        conv_core<128, 192, 28, 3, 5>(xtA, wl, cw1, acc, tid);
        write_xt<192, 72, 3, 5>(xtB, acc, cb1, tid);
    }
    __syncthreads();
    {
        f32x4 acc[2][5];
        conv_core<192, 128, 1, 2, 5>(xtB, wl, cw2, acc, tid);
        write_xt<128, 70, 2, 5>(xtA, acc, cb2, tid);
    }
    __syncthreads();
    {
        f32x4 acc[1][5];
        conv_core<128, 64, 1, 1, 5>(xtA, wl, cw3, acc, tid);
        write_xt<64, 68, 1, 5>(xtB, acc, cb3, tid);
    }
    __syncthreads();
    {
        f32x4 acc[1][5];
        conv_core<64, 64, 1, 1, 5>(xtB, wl, cw4, acc, tid);
        write_xt<64, 66, 1, 5>(xtA, acc, cb4, tid);
    }
    __syncthreads();
    {
        f32x4 acc[1][4];
        conv_core<64, 64, 1, 1, 4>(xtA, wl, cw5, acc, tid);
        const int lane = tid & 63, wid = tid >> 6;
        const int lr = lane & 15, lq = lane >> 4;
        const int cobase = wid * 16;
#pragma unroll
        for (int ni = 0; ni < 4; ++ni) {
            int l = ni * 16 + lr;
#pragma unroll
            for (int r = 0; r < 4; ++r) {
                int co = cobase + lq * 4 + r;
                float y = acc[0][ni][r] + cb5[co];
                S[co * 65 + l] = y * y + 0.001f;
            }
        }
    }
    __syncthreads();

    const int q = tid & 3, rid = tid >> 2;
    for (int it = 0; it < 10; ++it) {
        float p = 0.f;
#pragma unroll
        for (int j = 0; j < 16; ++j) p += S[rid * 65 + q * 16 + j];
        p += __shfl_xor(p, 1);
        p += __shfl_xor(p, 2);
        float inv = 1.0f / p;
#pragma unroll
        for (int j = 0; j < 16; ++j) S[rid * 65 + q * 16 + j] *= inv;
        __syncthreads();
        float c = 0.f;
#pragma unroll
        for (int i = 0; i < 16; ++i) c += S[(q * 16 + i) * 65 + rid];
        c += __shfl_xor(c, 1);
        c += __shfl_xor(c, 2);
        float invc = 1.0f / c;
#pragma unroll
        for (int i = 0; i < 16; ++i) S[(q * 16 + i) * 65 + rid] *= invc;
        __syncthreads();
    }

#pragma unroll
    for (int i = 0; i < 16; ++i) {
        int idx = i * 256 + tid;
        out[b * 4096 + idx] = S[(idx >> 6) * 65 + (idx & 63)];
    }
}

// ---------------------------------------------------------------------------
extern "C" void kernel_launch(void* const* d_in, const int* in_sizes, int n_in,
                              void* d_out, int out_size, void* d_ws, size_t ws_size,
                              hipStream_t stream) {
    const float* x = (const float*)d_in[0];
    const float* w1 = (const float*)d_in[1];
    const float* b1 = (const float*)d_in[2];
    const float* w2 = (const float*)d_in[3];
    const float* b2 = (const float*)d_in[4];
    const float* w3 = (const float*)d_in[5];
    const float* b3 = (const float*)d_in[6];
    const float* cw1 = (const float*)d_in[7];
    const float* cb1 = (const float*)d_in[8];
    const float* cw2 = (const float*)d_in[9];
    const float* cb2 = (const float*)d_in[10];
    const float* cw3 = (const float*)d_in[11];
    const float* cb3 = (const float*)d_in[12];
    const float* cw4 = (const float*)d_in[13];
    const float* cb4 = (const float*)d_in[14];
    const float* cw5 = (const float*)d_in[15];
    const float* cb5 = (const float*)d_in[16];
    float* out = (float*)d_out;

    char* ws = (char*)d_ws;
    float* h1 = (float*)(ws);             // 131072 B
    char* h2b = ws + 131072;              // 2 MB bf16 pre-swizzled image
    char* parts = ws + 131072 + 2097152;  // 2 x 8 MB bf16 partials

    gemm1_k<<<256, 128, 0, stream>>>(x, w1, b1, h1);
    gemm2_k<<<dim3(64, 4), 256, 0, stream>>>(h1, w2, b2, h2b);
    gemm3_k<<<512, 512, 0, stream>>>(h2b, w3, parts);
    convsink_k<<<256, 256, 0, stream>>>(parts, b3, cw1, cb1, cw2, cb2,
                                        cw3, cb3, cw4, cb4, cw5, cb5, out);
}